// Round 2
// baseline (457.003 us; speedup 1.0000x reference)
//
#include <hip/hip_runtime.h>
#include <hip/hip_bf16.h>

typedef __bf16 bf16x8 __attribute__((ext_vector_type(8)));
typedef __bf16 bf16x2 __attribute__((ext_vector_type(2)));
typedef float f32x4 __attribute__((ext_vector_type(4)));

#define NROWS 100000
#define NSTRIPS 6250   // 100000 / 16, exact
#define EPS 1e-5f
#define SLOPE 0.2f
#define INVN 1e-5f     // 1.0f / 100000

__device__ __forceinline__ bf16x8 cvt8(const float* s) {
    float4 x0 = *(const float4*)s, x1 = *(const float4*)(s + 4);
    bf16x8 o;
    o[0] = (__bf16)x0.x; o[1] = (__bf16)x0.y; o[2] = (__bf16)x0.z; o[3] = (__bf16)x0.w;
    o[4] = (__bf16)x1.x; o[5] = (__bf16)x1.y; o[6] = (__bf16)x1.z; o[7] = (__bf16)x1.w;
    return o;
}

// ---- streaming GEMM: Y = LeakyReLU(A @ W^T + bias), + column sum/sumsq --------
// Tall-skinny shape (M=100000, K<=256, N<=256): W-fragments live entirely in
// registers (per wave: NI*16 columns x full K). A streams from global straight
// into MFMA A-fragments. NO LDS, NO barriers.
// Round-2 change: occupancy via GRID, not prefetch. Round-1's 1-deep software
// prefetch REGRESSED (69->93us, VALUBusy down) -- per-wave chain depth was not
// the limit; resident-wave count was (512 blocks = 2 waves/SIMD of 8). This
// version restores the proven round-0 loop body and raises resident waves:
//   gemm1: 1536 blocks x 4 waves, bounds(256,6)  -> 24 waves/CU (was 8)
//   gemm2/3: 8-wave blocks (NI halved keeps W-frag regs/wave flat),
//            bounds(512,4) -> 16 waves/CU (was 8)
// A-frag: lane reads A[row0+l16][ks*32+quad*8 ..+8] (16B, 64B/row granularity).
// C/D: col = l16, row = quad*4 + reg.
template <int KT, int NI, int WAVES, int MINW, bool F32IN>
__global__ __launch_bounds__(WAVES * 64, MINW)
void gemm_stream(const __bf16* __restrict__ A, const float* __restrict__ A32,
                 const __bf16* __restrict__ W, const float* __restrict__ W32,
                 const float* __restrict__ bias, __bf16* __restrict__ Y,
                 float* __restrict__ sum, float* __restrict__ sumsq)
{
    constexpr int KS = KT / 32;
    constexpr int NCOLS = NI * 16 * WAVES;
    const int wave = threadIdx.x >> 6, lane = threadIdx.x & 63;
    const int quad = lane >> 4, l16 = lane & 15;
    const int c0 = wave * (NI * 16);

    // B-fragments for this wave's column slice, full K, in registers
    bf16x8 bfrag[NI][KS];
    float bcol[NI];
    #pragma unroll
    for (int ni = 0; ni < NI; ++ni) {
        int col = c0 + ni * 16 + l16;
        bcol[ni] = bias[col];
        #pragma unroll
        for (int ks = 0; ks < KS; ++ks) {
            int k = ks * 32 + quad * 8;
            if constexpr (F32IN) bfrag[ni][ks] = cvt8(W32 + (size_t)col * KT + k);
            else                 bfrag[ni][ks] = *(const bf16x8*)(W + (size_t)col * KT + k);
        }
    }

    float csum[NI] = {}, csq[NI] = {};

    for (int s = blockIdx.x; s < NSTRIPS; s += gridDim.x) {
        int row0 = s * 16;
        bf16x8 afrag[KS];
        #pragma unroll
        for (int ks = 0; ks < KS; ++ks) {
            int k = ks * 32 + quad * 8;
            if constexpr (F32IN) afrag[ks] = cvt8(A32 + (size_t)(row0 + l16) * KT + k);
            else                 afrag[ks] = *(const bf16x8*)(A + (size_t)(row0 + l16) * KT + k);
        }
        f32x4 acc[NI] = {};
        #pragma unroll
        for (int ks = 0; ks < KS; ++ks)
            #pragma unroll
            for (int ni = 0; ni < NI; ++ni)
                acc[ni] = __builtin_amdgcn_mfma_f32_16x16x32_bf16(
                    afrag[ks], bfrag[ni][ks], acc[ni], 0, 0, 0);

        #pragma unroll
        for (int ni = 0; ni < NI; ++ni) {
            int col = c0 + ni * 16 + l16;
            #pragma unroll
            for (int r = 0; r < 4; ++r) {
                float y = acc[ni][r] + bcol[ni];
                y = (y > 0.f) ? y : SLOPE * y;
                Y[(size_t)(row0 + quad * 4 + r) * NCOLS + col] = (__bf16)y;
                csum[ni] += y;
                csq[ni]  += y * y;
            }
        }
    }

    #pragma unroll
    for (int ni = 0; ni < NI; ++ni) {
        float s = csum[ni], q = csq[ni];
        s += __shfl_xor(s, 16); s += __shfl_xor(s, 32);
        q += __shfl_xor(q, 16); q += __shfl_xor(q, 32);
        if (quad == 0) {
            int col = c0 + ni * 16 + l16;
            atomicAdd(&sum[col], s);
            atomicAdd(&sumsq[col], q);
        }
    }
}

// ---- fused stats + fold: every block recomputes s,t from column sums (cheap),
// then folds BN into the next layer: W' = W*diag(s) (bf16), b' = b + W@t.
__global__ void fold_stats_k(const float* __restrict__ sum, const float* __restrict__ sumsq,
                             const float* __restrict__ g, const float* __restrict__ beta,
                             const float* __restrict__ W, const float* __restrict__ b,
                             __bf16* __restrict__ Wf, float* __restrict__ bf_, int K)
{
    __shared__ float s_sh[256], t_sh[256];
    const int n = blockIdx.x, lane = threadIdx.x;  // 64 threads = 1 wave
    for (int k = lane; k < K; k += 64) {
        float m = sum[k] * INVN;
        float v = sumsq[k] * INVN - m * m;
        float sc = g[k] * rsqrtf(v + EPS);
        s_sh[k] = sc;
        t_sh[k] = beta[k] - m * sc;
    }
    __syncthreads();
    float dot = 0.f;
    for (int k = lane; k < K; k += 64) {
        float w = W[(size_t)n * K + k];
        Wf[(size_t)n * K + k] = (__bf16)(w * s_sh[k]);
        dot += w * t_sh[k];
    }
    #pragma unroll
    for (int off = 32; off; off >>= 1) dot += __shfl_down(dot, off);
    if (lane == 0) bf_[n] = b[n] + dot;
}

// ---- fused finalize: one wave per node row.
//  * computes s3,t3 inline per lane from sum3/sq3 (drops stats_k + its bubble)
//  * F = Y3*s3 + t3  (the 'f' output, fp32)
//  * node_update = s3 * mean_k(Y3[neigh]) + t3  (BN after mean; linear)
__global__ __launch_bounds__(256)
void finalize_k(const __bf16* __restrict__ Y3, const int* __restrict__ idx,
                const float* __restrict__ sum3, const float* __restrict__ sq3,
                const float* __restrict__ g3, const float* __restrict__ be3,
                float* __restrict__ F, float* __restrict__ out, int N)
{
    const int row = blockIdx.x * 4 + (threadIdx.x >> 6);  // one row per wave
    if (row >= N) return;
    const int lane = threadIdx.x & 63;
    const int c = lane * 2;

    const float2 sm = *(const float2*)(sum3 + c);
    const float2 sq = *(const float2*)(sq3 + c);
    const float2 gg = *(const float2*)(g3 + c);
    const float2 bb = *(const float2*)(be3 + c);
    const float m0 = sm.x * INVN, m1 = sm.y * INVN;
    const float v0 = sq.x * INVN - m0 * m0, v1 = sq.y * INVN - m1 * m1;
    const float s0 = gg.x * rsqrtf(v0 + EPS), s1 = gg.y * rsqrtf(v1 + EPS);
    const float t0 = bb.x - m0 * s0, t1 = bb.y - m1 * s1;

    bf16x2 own = *(const bf16x2*)(Y3 + (size_t)row * 128 + c);
    float2 f;
    f.x = (float)own[0] * s0 + t0;
    f.y = (float)own[1] * s1 + t1;
    *(float2*)(F + (size_t)row * 128 + c) = f;

    const int* ib = idx + (size_t)row * 16;
    float a0 = 0.f, a1 = 0.f;
    #pragma unroll
    for (int k = 0; k < 16; ++k) {
        const int j = ib[k];  // wave-uniform -> scalar load
        bf16x2 v = *(const bf16x2*)(Y3 + (size_t)j * 128 + c);
        a0 += (float)v[0];
        a1 += (float)v[1];
    }
    float2 o;
    o.x = a0 * 0.0625f * s0 + t0;
    o.y = a1 * 0.0625f * s1 + t1;
    *(float2*)(out + (size_t)row * 128 + c) = o;
}

extern "C" void kernel_launch(void* const* d_in, const int* in_sizes, int n_in,
                              void* d_out, int out_size, void* d_ws, size_t ws_size,
                              hipStream_t stream)
{
    const float* X   = (const float*)d_in[0];
    const int*   idx = (const int*)d_in[1];
    // d_in[2] = prob_retained (unused, ==1)
    const float* W1  = (const float*)d_in[3];
    const float* b1  = (const float*)d_in[4];
    const float* g1  = (const float*)d_in[5];
    const float* be1 = (const float*)d_in[6];
    const float* W2  = (const float*)d_in[7];
    const float* b2  = (const float*)d_in[8];
    const float* g2  = (const float*)d_in[9];
    const float* be2 = (const float*)d_in[10];
    const float* W3  = (const float*)d_in[11];
    const float* b3  = (const float*)d_in[12];
    const float* g3  = (const float*)d_in[13];
    const float* be3 = (const float*)d_in[14];

    char* ws = (char*)d_ws;
    float* sum1 = (float*)(ws + 0);
    float* sq1  = (float*)(ws + 1024);
    float* sum2 = (float*)(ws + 2048);
    float* sq2  = (float*)(ws + 3072);
    float* sum3 = (float*)(ws + 4096);
    float* sq3  = (float*)(ws + 4608);
    float* b2f  = (float*)(ws + 10240);
    float* b3f  = (float*)(ws + 11264);
    __bf16* W2f = (__bf16*)(ws + 13312);            // 256*256*2 = 131072 B
    __bf16* W3f = (__bf16*)(ws + 144384);           // 128*256*2 = 65536 B
    __bf16* Y1  = (__bf16*)(ws + (1 << 20));                   // [N,256] bf16 51.2 MB
    __bf16* Y2  = (__bf16*)(ws + (1 << 20) + 51200000);        // [N,256] bf16 51.2 MB
    __bf16* Y3  = Y1;  // [N,128]; Y1 dead after gemm2 (gemm3 reads only Y2)

    float* out_nu = (float*)d_out;                  // node_update [N,128] fp32
    float* F      = out_nu + (size_t)NROWS * 128;   // f [N,128] fp32

    hipMemsetAsync(d_ws, 0, 5120, stream);  // zero sum/sumsq accumulators

    // layer 1: X[100000,128] @ W1[256,128]^T (fp32 converted inline)
    // 1536 blocks x 4 waves -> 6 blocks/CU resident (VGPR 68 <= 85 cap) = 24 waves/CU
    gemm_stream<128, 4, 4, 6, true><<<1536, 256, 0, stream>>>(
        nullptr, X, nullptr, W1, b1, Y1, sum1, sq1);
    fold_stats_k<<<256, 64, 0, stream>>>(sum1, sq1, g1, be1, W2, b2, W2f, b2f, 256);

    // layer 2: Y1[100000,256] @ W2'[256,256]^T -> Y2
    // 8-wave blocks, NI=2 (W-frag 64 VGPR/wave), bounds(512,4) -> 2 blocks/CU = 16 waves/CU
    gemm_stream<256, 2, 8, 4, false><<<512, 512, 0, stream>>>(
        Y1, nullptr, W2f, nullptr, b2f, Y2, sum2, sq2);
    fold_stats_k<<<128, 64, 0, stream>>>(sum2, sq2, g2, be2, W3, b3, W3f, b3f, 256);

    // layer 3: Y2[100000,256] @ W3'[128,256]^T -> raw Y3 (pre-BN) into Y1 region
    gemm_stream<256, 1, 8, 4, false><<<512, 512, 0, stream>>>(
        Y2, nullptr, W3f, nullptr, b3f, Y3, sum3, sq3);

    // fused: stats3 + f-output + neighbor-mean
    finalize_k<<<25000, 256, 0, stream>>>(Y3, idx, sum3, sq3, g3, be3, F, out_nu, NROWS);
}

// Round 3
// 390.192 us; speedup vs baseline: 1.1712x; 1.1712x over previous
//
#include <hip/hip_runtime.h>
#include <hip/hip_bf16.h>

typedef __bf16 bf16x8 __attribute__((ext_vector_type(8)));
typedef __bf16 bf16x2 __attribute__((ext_vector_type(2)));
typedef float f32x4 __attribute__((ext_vector_type(4)));

#define NROWS 100000
#define NSTRIPS 6250   // 100000 / 16, exact
#define EPS 1e-5f
#define SLOPE 0.2f
#define INVN 1e-5f     // 1.0f / 100000

__device__ __forceinline__ bf16x8 cvt8(const float* s) {
    float4 x0 = *(const float4*)s, x1 = *(const float4*)(s + 4);
    bf16x8 o;
    o[0] = (__bf16)x0.x; o[1] = (__bf16)x0.y; o[2] = (__bf16)x0.z; o[3] = (__bf16)x0.w;
    o[4] = (__bf16)x1.x; o[5] = (__bf16)x1.y; o[6] = (__bf16)x1.z; o[7] = (__bf16)x1.w;
    return o;
}

// ---- streaming GEMM: Y = LeakyReLU(A @ W^T + bias), + column sum/sumsq --------
// Round-3 diagnosis: VGPR_Count was 68/116/40 across rounds -- NEVER enough to
// hold bfrag (64 regs at NI=4). The compiler has been rematerializing the
// loop-invariant W loads INSIDE the strip loop every iteration (round 2's tight
// cap turned that into scratch spills: FETCH 25->134 MB, dur 128us). The "W in
// registers" premise never held.
// Fix: shrink the per-block column tile so W-frags genuinely fit with headroom:
//   * NI=2 per wave (32 cols/wave, 128 cols/block of 4 waves)
//   * blockIdx.y selects the column slice (N=256 -> y=2; A read twice, L3-served)
//   * bounds (256,4) for KT=128 (est ~110 regs < 128 cap)
//     bounds (256,3) for KT=256 (est ~124 regs < 170 cap)
// Occupancy: 16 waves/CU (gemm1) / 12 (gemm2,3) with TRUE register residency.
// A-frag: lane reads A[row0+l16][ks*32+quad*8 ..+8]. C/D: col=l16, row=quad*4+r.
template <int KT, int NI, int WAVES, int MINW, int NTOT, bool F32IN>
__global__ __launch_bounds__(WAVES * 64, MINW)
void gemm_stream(const __bf16* __restrict__ A, const float* __restrict__ A32,
                 const __bf16* __restrict__ W, const float* __restrict__ W32,
                 const float* __restrict__ bias, __bf16* __restrict__ Y,
                 float* __restrict__ sum, float* __restrict__ sumsq)
{
    constexpr int KS = KT / 32;
    const int wave = threadIdx.x >> 6, lane = threadIdx.x & 63;
    const int quad = lane >> 4, l16 = lane & 15;
    const int c0 = blockIdx.y * (NI * 16 * WAVES) + wave * (NI * 16);

    // W-fragments for this wave's column slice, full K, in registers
    bf16x8 bfrag[NI][KS];
    float bcol[NI];
    #pragma unroll
    for (int ni = 0; ni < NI; ++ni) {
        int col = c0 + ni * 16 + l16;
        bcol[ni] = bias[col];
        #pragma unroll
        for (int ks = 0; ks < KS; ++ks) {
            int k = ks * 32 + quad * 8;
            if constexpr (F32IN) bfrag[ni][ks] = cvt8(W32 + (size_t)col * KT + k);
            else                 bfrag[ni][ks] = *(const bf16x8*)(W + (size_t)col * KT + k);
        }
    }

    float csum[NI] = {}, csq[NI] = {};

    for (int s = blockIdx.x; s < NSTRIPS; s += gridDim.x) {
        int row0 = s * 16;
        bf16x8 afrag[KS];
        #pragma unroll
        for (int ks = 0; ks < KS; ++ks) {
            int k = ks * 32 + quad * 8;
            if constexpr (F32IN) afrag[ks] = cvt8(A32 + (size_t)(row0 + l16) * KT + k);
            else                 afrag[ks] = *(const bf16x8*)(A + (size_t)(row0 + l16) * KT + k);
        }
        f32x4 acc[NI] = {};
        #pragma unroll
        for (int ks = 0; ks < KS; ++ks)
            #pragma unroll
            for (int ni = 0; ni < NI; ++ni)
                acc[ni] = __builtin_amdgcn_mfma_f32_16x16x32_bf16(
                    afrag[ks], bfrag[ni][ks], acc[ni], 0, 0, 0);

        #pragma unroll
        for (int ni = 0; ni < NI; ++ni) {
            int col = c0 + ni * 16 + l16;
            #pragma unroll
            for (int r = 0; r < 4; ++r) {
                float y = acc[ni][r] + bcol[ni];
                y = (y > 0.f) ? y : SLOPE * y;
                Y[(size_t)(row0 + quad * 4 + r) * NTOT + col] = (__bf16)y;
                csum[ni] += y;
                csq[ni]  += y * y;
            }
        }
    }

    #pragma unroll
    for (int ni = 0; ni < NI; ++ni) {
        float s = csum[ni], q = csq[ni];
        s += __shfl_xor(s, 16); s += __shfl_xor(s, 32);
        q += __shfl_xor(q, 16); q += __shfl_xor(q, 32);
        if (quad == 0) {
            int col = c0 + ni * 16 + l16;
            atomicAdd(&sum[col], s);
            atomicAdd(&sumsq[col], q);
        }
    }
}

// ---- fused stats + fold: every block recomputes s,t from column sums (cheap),
// then folds BN into the next layer: W' = W*diag(s) (bf16), b' = b + W@t.
__global__ void fold_stats_k(const float* __restrict__ sum, const float* __restrict__ sumsq,
                             const float* __restrict__ g, const float* __restrict__ beta,
                             const float* __restrict__ W, const float* __restrict__ b,
                             __bf16* __restrict__ Wf, float* __restrict__ bf_, int K)
{
    __shared__ float s_sh[256], t_sh[256];
    const int n = blockIdx.x, lane = threadIdx.x;  // 64 threads = 1 wave
    for (int k = lane; k < K; k += 64) {
        float m = sum[k] * INVN;
        float v = sumsq[k] * INVN - m * m;
        float sc = g[k] * rsqrtf(v + EPS);
        s_sh[k] = sc;
        t_sh[k] = beta[k] - m * sc;
    }
    __syncthreads();
    float dot = 0.f;
    for (int k = lane; k < K; k += 64) {
        float w = W[(size_t)n * K + k];
        Wf[(size_t)n * K + k] = (__bf16)(w * s_sh[k]);
        dot += w * t_sh[k];
    }
    #pragma unroll
    for (int off = 32; off; off >>= 1) dot += __shfl_down(dot, off);
    if (lane == 0) bf_[n] = b[n] + dot;
}

// ---- fused finalize: one wave per node row.
//  * computes s3,t3 inline per lane from sum3/sq3
//  * F = Y3*s3 + t3  (the 'f' output, fp32)
//  * node_update = s3 * mean_k(Y3[neigh]) + t3  (BN after mean; linear)
__global__ __launch_bounds__(256)
void finalize_k(const __bf16* __restrict__ Y3, const int* __restrict__ idx,
                const float* __restrict__ sum3, const float* __restrict__ sq3,
                const float* __restrict__ g3, const float* __restrict__ be3,
                float* __restrict__ F, float* __restrict__ out, int N)
{
    const int row = blockIdx.x * 4 + (threadIdx.x >> 6);  // one row per wave
    if (row >= N) return;
    const int lane = threadIdx.x & 63;
    const int c = lane * 2;

    const float2 sm = *(const float2*)(sum3 + c);
    const float2 sq = *(const float2*)(sq3 + c);
    const float2 gg = *(const float2*)(g3 + c);
    const float2 bb = *(const float2*)(be3 + c);
    const float m0 = sm.x * INVN, m1 = sm.y * INVN;
    const float v0 = sq.x * INVN - m0 * m0, v1 = sq.y * INVN - m1 * m1;
    const float s0 = gg.x * rsqrtf(v0 + EPS), s1 = gg.y * rsqrtf(v1 + EPS);
    const float t0 = bb.x - m0 * s0, t1 = bb.y - m1 * s1;

    bf16x2 own = *(const bf16x2*)(Y3 + (size_t)row * 128 + c);
    float2 f;
    f.x = (float)own[0] * s0 + t0;
    f.y = (float)own[1] * s1 + t1;
    *(float2*)(F + (size_t)row * 128 + c) = f;

    const int* ib = idx + (size_t)row * 16;
    float a0 = 0.f, a1 = 0.f;
    #pragma unroll
    for (int k = 0; k < 16; ++k) {
        const int j = ib[k];  // wave-uniform -> scalar load
        bf16x2 v = *(const bf16x2*)(Y3 + (size_t)j * 128 + c);
        a0 += (float)v[0];
        a1 += (float)v[1];
    }
    float2 o;
    o.x = a0 * 0.0625f * s0 + t0;
    o.y = a1 * 0.0625f * s1 + t1;
    *(float2*)(out + (size_t)row * 128 + c) = o;
}

extern "C" void kernel_launch(void* const* d_in, const int* in_sizes, int n_in,
                              void* d_out, int out_size, void* d_ws, size_t ws_size,
                              hipStream_t stream)
{
    const float* X   = (const float*)d_in[0];
    const int*   idx = (const int*)d_in[1];
    // d_in[2] = prob_retained (unused, ==1)
    const float* W1  = (const float*)d_in[3];
    const float* b1  = (const float*)d_in[4];
    const float* g1  = (const float*)d_in[5];
    const float* be1 = (const float*)d_in[6];
    const float* W2  = (const float*)d_in[7];
    const float* b2  = (const float*)d_in[8];
    const float* g2  = (const float*)d_in[9];
    const float* be2 = (const float*)d_in[10];
    const float* W3  = (const float*)d_in[11];
    const float* b3  = (const float*)d_in[12];
    const float* g3  = (const float*)d_in[13];
    const float* be3 = (const float*)d_in[14];

    char* ws = (char*)d_ws;
    float* sum1 = (float*)(ws + 0);
    float* sq1  = (float*)(ws + 1024);
    float* sum2 = (float*)(ws + 2048);
    float* sq2  = (float*)(ws + 3072);
    float* sum3 = (float*)(ws + 4096);
    float* sq3  = (float*)(ws + 4608);
    float* b2f  = (float*)(ws + 10240);
    float* b3f  = (float*)(ws + 11264);
    __bf16* W2f = (__bf16*)(ws + 13312);            // 256*256*2 = 131072 B
    __bf16* W3f = (__bf16*)(ws + 144384);           // 128*256*2 = 65536 B
    __bf16* Y1  = (__bf16*)(ws + (1 << 20));                   // [N,256] bf16 51.2 MB
    __bf16* Y2  = (__bf16*)(ws + (1 << 20) + 51200000);        // [N,256] bf16 51.2 MB
    __bf16* Y3  = Y1;  // [N,128]; Y1 dead after gemm2 (gemm3 reads only Y2)

    float* out_nu = (float*)d_out;                  // node_update [N,128] fp32
    float* F      = out_nu + (size_t)NROWS * 128;   // f [N,128] fp32

    hipMemsetAsync(d_ws, 0, 5120, stream);  // zero sum/sumsq accumulators

    // layer 1: X[100000,128] @ W1[256,128]^T (fp32 converted inline)
    // 512x2 blocks (y = column slice), 4 waves, bounds(256,4) -> 16 waves/CU, no spill
    gemm_stream<128, 2, 4, 4, 256, true><<<dim3(512, 2), 256, 0, stream>>>(
        nullptr, X, nullptr, W1, b1, Y1, sum1, sq1);
    fold_stats_k<<<256, 64, 0, stream>>>(sum1, sq1, g1, be1, W2, b2, W2f, b2f, 256);

    // layer 2: Y1[100000,256] @ W2'[256,256]^T -> Y2
    // 384x2 blocks, bounds(256,3) -> 12 waves/CU (bfrag 64 regs resident)
    gemm_stream<256, 2, 4, 3, 256, false><<<dim3(384, 2), 256, 0, stream>>>(
        Y1, nullptr, W2f, nullptr, b2f, Y2, sum2, sq2);
    fold_stats_k<<<128, 64, 0, stream>>>(sum2, sq2, g2, be2, W3, b3, W3f, b3f, 256);

    // layer 3: Y2[100000,256] @ W3'[128,256]^T -> raw Y3 (pre-BN) into Y1 region
    gemm_stream<256, 2, 4, 3, 128, false><<<dim3(768, 1), 256, 0, stream>>>(
        Y2, nullptr, W3f, nullptr, b3f, Y3, sum3, sq3);

    // fused: stats3 + f-output + neighbor-mean
    finalize_k<<<25000, 256, 0, stream>>>(Y3, idx, sum3, sq3, g3, be3, F, out_nu, NROWS);
}